// Round 10
// baseline (129.790 us; speedup 1.0000x reference)
//
#include <hip/hip_runtime.h>
#include <hip/hip_bf16.h>

#define NB 16
#define LC 2048
#define LQ 256
#define DD 256
#define NEGINF -1e30f

typedef __attribute__((ext_vector_type(8))) short bf16x8;
typedef __attribute__((ext_vector_type(4))) float f32x4;

#define MFMA16(a, b, c) __builtin_amdgcn_mfma_f32_16x16x32_bf16((a), (b), (c), 0, 0, 0)

typedef const unsigned int __attribute__((address_space(1))) glb_u32;
typedef unsigned int __attribute__((address_space(3))) lds_u32;

__device__ __forceinline__ void gload_lds16(const void* g, void* l) {
    __builtin_amdgcn_global_load_lds((glb_u32*)g, (lds_u32*)l, 16, 0, 0);
}

__device__ __forceinline__ short f2b(float x) {
    unsigned u = __float_as_uint(x);
    unsigned r = (u + 0x7fffu + ((u >> 16) & 1u)) >> 16;
    return (short)r;
}
__device__ __forceinline__ float b2f(short s) {
    return __uint_as_float(((unsigned)(unsigned short)s) << 16);
}

// ---------- prep: c-blocks: c16 + s0c + out slab0. q-blocks: qw16/qT16/s1q ----------
#define NCB (NB * LC / 8)
__global__ __launch_bounds__(256) void prep(
        const float* __restrict__ c, const float* __restrict__ q,
        const float* __restrict__ c_w, const float* __restrict__ cqw,
        const float* __restrict__ q_w, const float* __restrict__ bias,
        short* __restrict__ c16, float* __restrict__ s0c,
        short* __restrict__ qw16, short* __restrict__ qT16,
        float* __restrict__ s1q, float* __restrict__ out) {
    __shared__ float T[64][65];
    int t = threadIdx.x;
    if (blockIdx.x < NCB) {
        int row = blockIdx.x * 8 + (t >> 5);
        int k = t & 31;
        const float* src = c + (size_t)row * DD + k * 8;
        float4 v0 = *(const float4*)(src);
        float4 v1 = *(const float4*)(src + 4);
        float4 w0 = *(const float4*)(c_w + k * 8);
        float4 w1 = *(const float4*)(c_w + k * 8 + 4);
        float s = v0.x * w0.x + v0.y * w0.y + v0.z * w0.z + v0.w * w0.w
                + v1.x * w1.x + v1.y * w1.y + v1.z * w1.z + v1.w * w1.w;
        #pragma unroll
        for (int o = 16; o > 0; o >>= 1) s += __shfl_xor(s, o, 64);
        if (k == 0) s0c[row] = s;
        // out slab 0: exact fp32 copy of c
        size_t ob = (size_t)row * (size_t)(4 * DD) + k * 8;
        *(float4*)(out + ob)     = v0;
        *(float4*)(out + ob + 4) = v1;
        ushort4 o0, o1;
        o0.x = (unsigned short)f2b(v0.x); o0.y = (unsigned short)f2b(v0.y);
        o0.z = (unsigned short)f2b(v0.z); o0.w = (unsigned short)f2b(v0.w);
        o1.x = (unsigned short)f2b(v1.x); o1.y = (unsigned short)f2b(v1.y);
        o1.z = (unsigned short)f2b(v1.z); o1.w = (unsigned short)f2b(v1.w);
        ushort4* dst = (ushort4*)(c16 + (size_t)row * DD + k * 8);
        dst[0] = o0;
        dst[1] = o1;
    } else {
        int idx = blockIdx.x - NCB;
        int b = idx >> 2, j0 = (idx & 3) * 64;
        int dd = t & 63, rg = t >> 6;
        float acc[16];
        #pragma unroll
        for (int i = 0; i < 16; ++i) acc[i] = 0.f;
        for (int dc = 0; dc < 4; ++dc) {
            float wv = cqw[dc * 64 + dd];
            float qwv = q_w[dc * 64 + dd];
            #pragma unroll
            for (int rr = 0; rr < 16; ++rr) {
                int r = rg + 4 * rr;
                float v = q[((size_t)b * LQ + j0 + r) * DD + dc * 64 + dd];
                qw16[((size_t)b * LQ + j0 + r) * DD + dc * 64 + dd] = f2b(v * wv);
                acc[rr] += v * qwv;
                T[dd][r] = v;
            }
            __syncthreads();
            int jj = t & 63;
            for (int dw = t >> 6; dw < 64; dw += 4)
                qT16[((size_t)b * DD + dc * 64 + dw) * LQ + j0 + jj] = f2b(T[dw][jj]);
            __syncthreads();
        }
        float bv = bias[0];
        #pragma unroll
        for (int rr = 0; rr < 16; ++rr) {
            float s = acc[rr];
            #pragma unroll
            for (int o = 32; o > 0; o >>= 1) s += __shfl_xor(s, o, 64);
            if (dd == 0) s1q[b * LQ + j0 + rg + 4 * rr] = s + bv;
        }
    }
}

// ---------- k1: S tile [128 x 256] = c @ (q*cqw)^T + s0 + s1 (8 waves)
// outputs: P1b [i][j] = bf16(finished row softmax), wgtg = cm*exp(rowC), pm/ps
__global__ __launch_bounds__(512) void k1_S(
        const short* __restrict__ c16, const short* __restrict__ qw16,
        const float* __restrict__ cmask, const float* __restrict__ qmask,
        const float* __restrict__ s0c, const float* __restrict__ s1q,
        short* __restrict__ P1b, float* __restrict__ wgtg,
        float* __restrict__ pm, float* __restrict__ ps) {
    __shared__ short As[128 * 64];
    __shared__ short Bs[256 * 64];
    __shared__ float rmLds[128 * 4];
    __shared__ float rsLds[128 * 4];
    __shared__ float rowCLds[128];
    int b  = blockIdx.y;
    int i0 = blockIdx.x * 128;
    int t = threadIdx.x;
    int l = t & 63, w = t >> 6;
    int wr = w >> 2, wc = w & 3;

    f32x4 acc[4][4];
    #pragma unroll
    for (int m = 0; m < 4; ++m)
        #pragma unroll
        for (int n = 0; n < 4; ++n) acc[m][n] = (f32x4){0.f, 0.f, 0.f, 0.f};

    const short* Ag = c16  + ((size_t)b * LC + i0) * DD;
    const short* Bg = qw16 + ((size_t)b * LQ) * DD;
    int lrow = l >> 3;
    int lcolsw = ((l & 7) ^ lrow) * 8;

    for (int kt = 0; kt < DD; kt += 64) {
        __syncthreads();
        #pragma unroll
        for (int r = 0; r < 2; ++r) {
            int chunk = r * 8 + w;
            int row = chunk * 8 + lrow;
            gload_lds16(Ag + (size_t)row * DD + kt + lcolsw, As + chunk * 512);
        }
        #pragma unroll
        for (int r = 0; r < 4; ++r) {
            int chunk = r * 8 + w;
            int row = chunk * 8 + lrow;
            gload_lds16(Bg + (size_t)row * DD + kt + lcolsw, Bs + chunk * 512);
        }
        __syncthreads();
        #pragma unroll
        for (int kf = 0; kf < 2; ++kf) {
            bf16x8 a[4], bb[4];
            #pragma unroll
            for (int m = 0; m < 4; ++m) {
                int row = wr * 64 + m * 16 + (l & 15);
                int byte = row * 128 + kf * 64 + (l >> 4) * 16;
                a[m] = *(const bf16x8*)((const char*)As + (byte ^ ((row & 7) << 4)));
            }
            #pragma unroll
            for (int n = 0; n < 4; ++n) {
                int row = wc * 64 + n * 16 + (l & 15);
                int byte = row * 128 + kf * 64 + (l >> 4) * 16;
                bb[n] = *(const bf16x8*)((const char*)Bs + (byte ^ ((row & 7) << 4)));
            }
            #pragma unroll
            for (int m = 0; m < 4; ++m)
                #pragma unroll
                for (int n = 0; n < 4; ++n)
                    acc[m][n] = MFMA16(a[m], bb[n], acc[m][n]);
        }
    }

    // ---- epilogue: add s0c + s1q (keep fp32 S in acc)
    float s1v[4], qmv[4], negq[4];
    #pragma unroll
    for (int n = 0; n < 4; ++n) {
        int j = wc * 64 + n * 16 + (l & 15);
        s1v[n] = s1q[b * LQ + j];
        qmv[n] = qmask[b * LQ + j];
        negq[n] = (1.f - qmv[n]) * NEGINF;
    }
    float s0r[4][4], cmr[4][4];
    #pragma unroll
    for (int m = 0; m < 4; ++m)
        #pragma unroll
        for (int reg = 0; reg < 4; ++reg) {
            int il = wr * 64 + m * 16 + (l >> 4) * 4 + reg;
            s0r[m][reg] = s0c[b * LC + i0 + il];
            cmr[m][reg] = cmask[b * LC + i0 + il];
        }
    #pragma unroll
    for (int m = 0; m < 4; ++m)
        #pragma unroll
        for (int n = 0; n < 4; ++n)
            #pragma unroll
            for (int reg = 0; reg < 4; ++reg)
                acc[m][n][reg] = acc[m][n][reg] + s0r[m][reg] + s1v[n];

    // ---- column-softmax partial stats (over 128 i-rows, c_mask applied)
    #pragma unroll
    for (int n = 0; n < 4; ++n) {
        float x2v[16];
        float mx = NEGINF;
        #pragma unroll
        for (int m = 0; m < 4; ++m)
            #pragma unroll
            for (int reg = 0; reg < 4; ++reg) {
                float cm = cmr[m][reg];
                float x2 = acc[m][n][reg] * cm + (1.f - cm) * NEGINF;
                x2v[m * 4 + reg] = x2;
                mx = fmaxf(mx, x2);
            }
        float ss = 0.f;
        #pragma unroll
        for (int e = 0; e < 16; ++e) ss += __expf(x2v[e] - mx);
        #pragma unroll
        for (int off = 16; off <= 32; off <<= 1) {
            float om = __shfl_xor(mx, off, 64);
            float os = __shfl_xor(ss, off, 64);
            float nm = fmaxf(mx, om);
            ss = ss * __expf(mx - nm) + os * __expf(om - nm);
            mx = nm;
        }
        if (l < 16) {
            size_t idx = ((size_t)b * 32 + blockIdx.x * 2 + wr) * LQ + wc * 64 + n * 16 + l;
            pm[idx] = mx;
            ps[idx] = ss;
        }
    }

    // ---- row-softmax stats: reduce over n (in-thread), l&15 (shfl), wc (LDS)
    #pragma unroll
    for (int m = 0; m < 4; ++m)
        #pragma unroll
        for (int reg = 0; reg < 4; ++reg) {
            float mx = NEGINF;
            #pragma unroll
            for (int n = 0; n < 4; ++n)
                mx = fmaxf(mx, fmaf(acc[m][n][reg], qmv[n], negq[n]));
            #pragma unroll
            for (int o = 1; o <= 8; o <<= 1) mx = fmaxf(mx, __shfl_xor(mx, o, 64));
            float ss = 0.f;
            #pragma unroll
            for (int n = 0; n < 4; ++n)
                ss += __expf(fmaf(acc[m][n][reg], qmv[n], negq[n]) - mx);
            #pragma unroll
            for (int o = 1; o <= 8; o <<= 1) ss += __shfl_xor(ss, o, 64);
            if ((l & 15) == 0) {
                int row = wr * 64 + m * 16 + (l >> 4) * 4 + reg;
                rmLds[row * 4 + wc] = mx;
                rsLds[row * 4 + wc] = ss;
            }
        }
    __syncthreads();
    if (t < 128) {
        float m0 = rmLds[t * 4 + 0], m1 = rmLds[t * 4 + 1];
        float m2 = rmLds[t * 4 + 2], m3 = rmLds[t * 4 + 3];
        float mm = fmaxf(fmaxf(m0, m1), fmaxf(m2, m3));
        float ss = rsLds[t * 4 + 0] * __expf(m0 - mm)
                 + rsLds[t * 4 + 1] * __expf(m1 - mm)
                 + rsLds[t * 4 + 2] * __expf(m2 - mm)
                 + rsLds[t * 4 + 3] * __expf(m3 - mm);
        float rc = mm + logf(ss);
        rowCLds[t] = rc;
        wgtg[(size_t)b * LC + i0 + t] = cmask[b * LC + i0 + t] * __expf(rc);
    }
    __syncthreads();

    // ---- P1b [i][j]: finished row softmax, bf16
    float rCv[4][4];
    #pragma unroll
    for (int m = 0; m < 4; ++m)
        #pragma unroll
        for (int reg = 0; reg < 4; ++reg)
            rCv[m][reg] = rowCLds[wr * 64 + m * 16 + (l >> 4) * 4 + reg];
    #pragma unroll
    for (int m = 0; m < 4; ++m)
        #pragma unroll
        for (int n = 0; n < 4; ++n)
            #pragma unroll
            for (int reg = 0; reg < 4; ++reg) {
                float p = __expf(fmaf(acc[m][n][reg], qmv[n], negq[n]) - rCv[m][reg]);
                int il = wr * 64 + m * 16 + (l >> 4) * 4 + reg;
                int j = wc * 64 + n * 16 + (l & 15);
                P1b[((size_t)b * LC + i0 + il) * LQ + j] = f2b(p);
            }
}

// ---------- k3: full-K GEMM  A2CT[d,j] = exp(-colC_j) * sum_i c[i,d]*(wgt_i*P1[i,j])
// colC fused in prologue; register-prefetch double-buffered staging.
#define K3S 72
__global__ __launch_bounds__(256) void k3_A2C(
        const short* __restrict__ c16, const short* __restrict__ P1b,
        const float* __restrict__ wgtg,
        const float* __restrict__ pm, const float* __restrict__ ps,
        short* __restrict__ A2CT) {
    __shared__ short As[128 * K3S];   // [d][i]
    __shared__ short Bs[128 * K3S];   // [j][i]
    __shared__ float colCs[128];
    int b  = blockIdx.y;
    int d0 = (blockIdx.x >> 1) * 128;
    int j0 = (blockIdx.x & 1) * 128;
    int t = threadIdx.x, l = t & 63, w = t >> 6;
    int wr = w >> 1, wc = w & 1;

    // colC = m + log(Z) for this block's 128 j columns
    if (t < 128) {
        float m = NEGINF, s = 0.f;
        for (int ch = 0; ch < 32; ++ch) {
            float pmv = pm[((size_t)b * 32 + ch) * LQ + j0 + t];
            float psv = ps[((size_t)b * 32 + ch) * LQ + j0 + t];
            float mn = fmaxf(m, pmv);
            s = s * __expf(m - mn) + psv * __expf(pmv - mn);
            m = mn;
        }
        colCs[t] = m + logf(s);
    }

    f32x4 acc[4][4];
    #pragma unroll
    for (int m = 0; m < 4; ++m)
        #pragma unroll
        for (int n = 0; n < 4; ++n) acc[m][n] = (f32x4){0.f, 0.f, 0.f, 0.f};

    int ii4 = (t >> 4) * 4;                 // i base (4 rows per thread)
    int c8  = (t & 15) * 8;                 // d/j col-block base (8 cols)
    int ip  = ii4 ^ (((c8 >> 3) & 7) << 3); // swizzled i base
    const size_t gbase = (size_t)b * LC;

    bf16x8 avA[4], pvA[4]; float wvA[4];
    bf16x8 avB[4], pvB[4]; float wvB[4];

    #pragma unroll
    for (int r = 0; r < 4; ++r) {           // initial load, k=0
        size_t gi = gbase + ii4 + r;
        avA[r] = *(const bf16x8*)(c16 + gi * DD + d0 + c8);
        pvA[r] = *(const bf16x8*)(P1b + gi * LQ + j0 + c8);
        wvA[r] = wgtg[gi];
    }

    for (int k0 = 0; k0 < LC; k0 += 128) {
        // ---- phase A: store A regs -> LDS, prefetch k0+64 into B regs
        __syncthreads();
        #pragma unroll
        for (int g = 0; g < 8; ++g) {
            short4 a4, b4;
            a4.x = avA[0][g]; a4.y = avA[1][g]; a4.z = avA[2][g]; a4.w = avA[3][g];
            b4.x = f2b(b2f(pvA[0][g]) * wvA[0]);
            b4.y = f2b(b2f(pvA[1][g]) * wvA[1]);
            b4.z = f2b(b2f(pvA[2][g]) * wvA[2]);
            b4.w = f2b(b2f(pvA[3][g]) * wvA[3]);
            *(short4*)(&As[(c8 + g) * K3S + ip]) = a4;
            *(short4*)(&Bs[(c8 + g) * K3S + ip]) = b4;
        }
        #pragma unroll
        for (int r = 0; r < 4; ++r) {
            size_t gi = gbase + k0 + 64 + ii4 + r;
            avB[r] = *(const bf16x8*)(c16 + gi * DD + d0 + c8);
            pvB[r] = *(const bf16x8*)(P1b + gi * LQ + j0 + c8);
            wvB[r] = wgtg[gi];
        }
        __syncthreads();
        #pragma unroll
        for (int kf = 0; kf < 2; ++kf) {
            bf16x8 a[4], bb[4];
            int colL = kf * 32 + (l >> 4) * 8;
            #pragma unroll
            for (int m = 0; m < 4; ++m) {
                int row = wr * 64 + m * 16 + (l & 15);
                int colP = colL ^ (((row >> 3) & 7) << 3);
                a[m] = *(const bf16x8*)((const char*)As + row * (K3S * 2) + colP * 2);
            }
            #pragma unroll
            for (int n = 0; n < 4; ++n) {
                int row = wc * 64 + n * 16 + (l & 15);
                int colP = colL ^ (((row >> 3) & 7) << 3);
                bb[n] = *(const bf16x8*)((const char*)Bs + row * (K3S * 2) + colP * 2);
            }
            #pragma unroll
            for (int m = 0; m < 4; ++m)
                #pragma unroll
                for (int n = 0; n < 4; ++n)
                    acc[m][n] = MFMA16(a[m], bb[n], acc[m][n]);
        }
        // ---- phase B: store B regs -> LDS, prefetch k0+128 into A regs
        __syncthreads();
        #pragma unroll
        for (int g = 0; g < 8; ++g) {
            short4 a4, b4;
            a4.x = avB[0][g]; a4.y = avB[1][g]; a4.z = avB[2][g]; a4.w = avB[3][g];
            b4.x = f2b(b2f(pvB[0][g]) * wvB[0]);
            b4.y = f2b(b2f(pvB[1][g]) * wvB[1]);
            b4.z = f2b(b2f(pvB[2][g]) * wvB[2]);
            b4.w = f2b(b2f(pvB[3][g]) * wvB[3]);
            *(short4*)(&As[(c8 + g) * K3S + ip]) = a4;
            *(short4*)(&Bs[(c8 + g) * K3S + ip]) = b4;
        }
        if (k0 + 128 < LC) {
            #pragma unroll
            for (int r = 0; r < 4; ++r) {
                size_t gi = gbase + k0 + 128 + ii4 + r;
                avA[r] = *(const bf16x8*)(c16 + gi * DD + d0 + c8);
                pvA[r] = *(const bf16x8*)(P1b + gi * LQ + j0 + c8);
                wvA[r] = wgtg[gi];
            }
        }
        __syncthreads();
        #pragma unroll
        for (int kf = 0; kf < 2; ++kf) {
            bf16x8 a[4], bb[4];
            int colL = kf * 32 + (l >> 4) * 8;
            #pragma unroll
            for (int m = 0; m < 4; ++m) {
                int row = wr * 64 + m * 16 + (l & 15);
                int colP = colL ^ (((row >> 3) & 7) << 3);
                a[m] = *(const bf16x8*)((const char*)As + row * (K3S * 2) + colP * 2);
            }
            #pragma unroll
            for (int n = 0; n < 4; ++n) {
                int row = wc * 64 + n * 16 + (l & 15);
                int colP = colL ^ (((row >> 3) & 7) << 3);
                bb[n] = *(const bf16x8*)((const char*)Bs + row * (K3S * 2) + colP * 2);
            }
            #pragma unroll
            for (int m = 0; m < 4; ++m)
                #pragma unroll
                for (int n = 0; n < 4; ++n)
                    acc[m][n] = MFMA16(a[m], bb[n], acc[m][n]);
        }
    }

    // epilogue: apply exp(-colC_j), write bf16 A2CT
    float ec[4];
    #pragma unroll
    for (int n = 0; n < 4; ++n)
        ec[n] = __expf(-colCs[wc * 64 + n * 16 + (l & 15)]);
    #pragma unroll
    for (int m = 0; m < 4; ++m)
        #pragma unroll
        for (int n = 0; n < 4; ++n)
            #pragma unroll
            for (int reg = 0; reg < 4; ++reg) {
                int d = d0 + wr * 64 + m * 16 + (l >> 4) * 4 + reg;
                int j = j0 + wc * 64 + n * 16 + (l & 15);
                A2CT[((size_t)b * DD + d) * LQ + j] = f2b(acc[m][n][reg] * ec[n]);
            }
}

// ---------- k4: pure GEMM  C2Q = P1@q, Q2C = P1@A2C; writes slabs 1,2,3 ----------
__global__ __launch_bounds__(256) void k4_out(
        const short* __restrict__ P1b, const short* __restrict__ qT16,
        const short* __restrict__ A2CT, const short* __restrict__ c16,
        float* __restrict__ out) {
    __shared__ float Lo1[16][260];
    __shared__ float Lo2[16][260];
    int b = blockIdx.y, i0 = blockIdx.x * 64;
    int t = threadIdx.x, l = t & 63, w = t >> 6;
    int d0w = w * 64;

    f32x4 acc1[4][4], acc2[4][4];
    #pragma unroll
    for (int m = 0; m < 4; ++m)
        #pragma unroll
        for (int n = 0; n < 4; ++n) {
            acc1[m][n] = (f32x4){0.f, 0.f, 0.f, 0.f};
            acc2[m][n] = (f32x4){0.f, 0.f, 0.f, 0.f};
        }
    const short* Sr  = P1b  + ((size_t)b * LC + i0) * LQ;
    const short* qTb = qT16 + (size_t)b * DD * LQ;
    const short* aTb = A2CT + (size_t)b * DD * LQ;

    #pragma unroll 2
    for (int kf = 0; kf < 8; ++kf) {
        int j8 = kf * 32 + (l >> 4) * 8;
        bf16x8 a[4];
        #pragma unroll
        for (int m = 0; m < 4; ++m)
            a[m] = *(const bf16x8*)(Sr + (size_t)(m * 16 + (l & 15)) * LQ + j8);
        #pragma unroll
        for (int n = 0; n < 4; ++n) {
            int d = d0w + n * 16 + (l & 15);
            size_t off = (size_t)d * LQ + j8;
            bf16x8 bq = *(const bf16x8*)(qTb + off);
            bf16x8 ba = *(const bf16x8*)(aTb + off);
            #pragma unroll
            for (int m = 0; m < 4; ++m) {
                acc1[m][n] = MFMA16(a[m], bq, acc1[m][n]);
                acc2[m][n] = MFMA16(a[m], ba, acc2[m][n]);
            }
        }
    }

    const short* cb16 = c16 + (size_t)b * LC * DD;
    #pragma unroll
    for (int m = 0; m < 4; ++m) {
        __syncthreads();
        #pragma unroll
        for (int n = 0; n < 4; ++n) {
            int col = d0w + n * 16 + (l & 15);
            #pragma unroll
            for (int reg = 0; reg < 4; ++reg) {
                int row = (l >> 4) * 4 + reg;
                Lo1[row][col] = acc1[m][n][reg];
                Lo2[row][col] = acc2[m][n][reg];
            }
        }
        __syncthreads();
        #pragma unroll
        for (int rr = 0; rr < 4; ++rr) {
            int row = w * 4 + rr;
            int i = i0 + m * 16 + row;
            float4 f1 = *(const float4*)&Lo1[row][l * 4];
            float4 f2 = *(const float4*)&Lo2[row][l * 4];
            short4 cu = *(const short4*)(cb16 + (size_t)i * DD + l * 4);
            float c0 = b2f(cu.x), c1 = b2f(cu.y), c2 = b2f(cu.z), c3 = b2f(cu.w);
            size_t ob = ((size_t)b * LC + i) * (size_t)(4 * DD);
            float4 p1 = {c0 * f1.x, c1 * f1.y, c2 * f1.z, c3 * f1.w};
            float4 p2 = {c0 * f2.x, c1 * f2.y, c2 * f2.z, c3 * f2.w};
            *(float4*)(out + ob + 256 + l * 4) = f1;
            *(float4*)(out + ob + 512 + l * 4) = p1;
            *(float4*)(out + ob + 768 + l * 4) = p2;
        }
    }
}

extern "C" void kernel_launch(void* const* d_in, const int* in_sizes, int n_in,
                              void* d_out, int out_size, void* d_ws, size_t ws_size,
                              hipStream_t stream) {
    const float* c     = (const float*)d_in[0];
    const float* q     = (const float*)d_in[1];
    const float* cmask = (const float*)d_in[2];
    const float* qmask = (const float*)d_in[3];
    const float* cqw   = (const float*)d_in[4];
    const float* c_w   = (const float*)d_in[5];
    const float* q_w   = (const float*)d_in[6];
    const float* bias  = (const float*)d_in[7];
    float* out = (float*)d_out;

    char* w = (char*)d_ws;
    short* P1b   = (short*)(w);                  // 16,777,216 B  [i][j]
    short* c16   = (short*)(w + 16777216);       // 16,777,216 B  [i][d]
    short* qw16  = (short*)(w + 33554432);       //  2,097,152 B
    short* qT16  = (short*)(w + 35651584);       //  2,097,152 B
    short* A2CT  = (short*)(w + 37748736);       //  2,097,152 B
    float* s0c   = (float*)(w + 39845888);       //    131,072 B
    float* s1q   = (float*)(w + 39976960);       //     16,384 B
    float* pm    = (float*)(w + 39993344);       //    524,288 B
    float* ps    = (float*)(w + 40517632);       //    524,288 B
    float* wgtg  = (float*)(w + 41041920);       //    131,072 B (end 41,172,992)

    prep<<<dim3(NCB + NB * LQ / 64), dim3(256), 0, stream>>>(
        c, q, c_w, cqw, q_w, bias, c16, s0c, qw16, qT16, s1q, out);
    k1_S<<<dim3(LC / 128, NB), dim3(512), 0, stream>>>(
        c16, qw16, cmask, qmask, s0c, s1q, P1b, wgtg, pm, ps);
    k3_A2C<<<dim3(4, NB), dim3(256), 0, stream>>>(
        c16, P1b, wgtg, pm, ps, A2CT);
    k4_out<<<dim3(LC / 64, NB), dim3(256), 0, stream>>>(
        P1b, qT16, A2CT, c16, out);
}

// Round 11
// 117.927 us; speedup vs baseline: 1.1006x; 1.1006x over previous
//
#include <hip/hip_runtime.h>
#include <hip/hip_bf16.h>

#define NB 16
#define LC 2048
#define LQ 256
#define DD 256
#define NEGINF -1e30f

typedef __attribute__((ext_vector_type(8))) short bf16x8;
typedef __attribute__((ext_vector_type(4))) float f32x4;

#define MFMA16(a, b, c) __builtin_amdgcn_mfma_f32_16x16x32_bf16((a), (b), (c), 0, 0, 0)

typedef const unsigned int __attribute__((address_space(1))) glb_u32;
typedef unsigned int __attribute__((address_space(3))) lds_u32;

__device__ __forceinline__ void gload_lds16(const void* g, void* l) {
    __builtin_amdgcn_global_load_lds((glb_u32*)g, (lds_u32*)l, 16, 0, 0);
}

__device__ __forceinline__ short f2b(float x) {
    unsigned u = __float_as_uint(x);
    unsigned r = (u + 0x7fffu + ((u >> 16) & 1u)) >> 16;
    return (short)r;
}
__device__ __forceinline__ float b2f(short s) {
    return __uint_as_float(((unsigned)(unsigned short)s) << 16);
}

// ---------- prep: c-blocks: c16 + s0c + out slab0. q-blocks: qw16/qT16/s1q ----------
#define NCB (NB * LC / 8)
__global__ __launch_bounds__(256) void prep(
        const float* __restrict__ c, const float* __restrict__ q,
        const float* __restrict__ c_w, const float* __restrict__ cqw,
        const float* __restrict__ q_w, const float* __restrict__ bias,
        short* __restrict__ c16, float* __restrict__ s0c,
        short* __restrict__ qw16, short* __restrict__ qT16,
        float* __restrict__ s1q, float* __restrict__ out) {
    __shared__ float T[64][65];
    int t = threadIdx.x;
    if (blockIdx.x < NCB) {
        int row = blockIdx.x * 8 + (t >> 5);
        int k = t & 31;
        const float* src = c + (size_t)row * DD + k * 8;
        float4 v0 = *(const float4*)(src);
        float4 v1 = *(const float4*)(src + 4);
        float4 w0 = *(const float4*)(c_w + k * 8);
        float4 w1 = *(const float4*)(c_w + k * 8 + 4);
        float s = v0.x * w0.x + v0.y * w0.y + v0.z * w0.z + v0.w * w0.w
                + v1.x * w1.x + v1.y * w1.y + v1.z * w1.z + v1.w * w1.w;
        #pragma unroll
        for (int o = 16; o > 0; o >>= 1) s += __shfl_xor(s, o, 64);
        if (k == 0) s0c[row] = s;
        size_t ob = (size_t)row * (size_t)(4 * DD) + k * 8;
        *(float4*)(out + ob)     = v0;
        *(float4*)(out + ob + 4) = v1;
        ushort4 o0, o1;
        o0.x = (unsigned short)f2b(v0.x); o0.y = (unsigned short)f2b(v0.y);
        o0.z = (unsigned short)f2b(v0.z); o0.w = (unsigned short)f2b(v0.w);
        o1.x = (unsigned short)f2b(v1.x); o1.y = (unsigned short)f2b(v1.y);
        o1.z = (unsigned short)f2b(v1.z); o1.w = (unsigned short)f2b(v1.w);
        ushort4* dst = (ushort4*)(c16 + (size_t)row * DD + k * 8);
        dst[0] = o0;
        dst[1] = o1;
    } else {
        int idx = blockIdx.x - NCB;
        int b = idx >> 2, j0 = (idx & 3) * 64;
        int dd = t & 63, rg = t >> 6;
        float acc[16];
        #pragma unroll
        for (int i = 0; i < 16; ++i) acc[i] = 0.f;
        for (int dc = 0; dc < 4; ++dc) {
            float wv = cqw[dc * 64 + dd];
            float qwv = q_w[dc * 64 + dd];
            #pragma unroll
            for (int rr = 0; rr < 16; ++rr) {
                int r = rg + 4 * rr;
                float v = q[((size_t)b * LQ + j0 + r) * DD + dc * 64 + dd];
                qw16[((size_t)b * LQ + j0 + r) * DD + dc * 64 + dd] = f2b(v * wv);
                acc[rr] += v * qwv;
                T[dd][r] = v;
            }
            __syncthreads();
            int jj = t & 63;
            for (int dw = t >> 6; dw < 64; dw += 4)
                qT16[((size_t)b * DD + dc * 64 + dw) * LQ + j0 + jj] = f2b(T[dw][jj]);
            __syncthreads();
        }
        float bv = bias[0];
        #pragma unroll
        for (int rr = 0; rr < 16; ++rr) {
            float s = acc[rr];
            #pragma unroll
            for (int o = 32; o > 0; o >>= 1) s += __shfl_xor(s, o, 64);
            if (dd == 0) s1q[b * LQ + j0 + rg + 4 * rr] = s + bv;
        }
    }
}

// ---------- k1: S tile [128 x 256] = c @ (q*cqw)^T + s0 + s1 (8 waves)
// outputs: P1b [i][j] = bf16(finished row softmax), wgtg = cm*exp(rowC), pm/ps
__global__ __launch_bounds__(512) void k1_S(
        const short* __restrict__ c16, const short* __restrict__ qw16,
        const float* __restrict__ cmask, const float* __restrict__ qmask,
        const float* __restrict__ s0c, const float* __restrict__ s1q,
        short* __restrict__ P1b, float* __restrict__ wgtg,
        float* __restrict__ pm, float* __restrict__ ps) {
    __shared__ short As[128 * 64];
    __shared__ short Bs[256 * 64];
    __shared__ float rmLds[128 * 4];
    __shared__ float rsLds[128 * 4];
    __shared__ float rowCLds[128];
    int b  = blockIdx.y;
    int i0 = blockIdx.x * 128;
    int t = threadIdx.x;
    int l = t & 63, w = t >> 6;
    int wr = w >> 2, wc = w & 3;

    f32x4 acc[4][4];
    #pragma unroll
    for (int m = 0; m < 4; ++m)
        #pragma unroll
        for (int n = 0; n < 4; ++n) acc[m][n] = (f32x4){0.f, 0.f, 0.f, 0.f};

    const short* Ag = c16  + ((size_t)b * LC + i0) * DD;
    const short* Bg = qw16 + ((size_t)b * LQ) * DD;
    int lrow = l >> 3;
    int lcolsw = ((l & 7) ^ lrow) * 8;

    for (int kt = 0; kt < DD; kt += 64) {
        __syncthreads();
        #pragma unroll
        for (int r = 0; r < 2; ++r) {
            int chunk = r * 8 + w;
            int row = chunk * 8 + lrow;
            gload_lds16(Ag + (size_t)row * DD + kt + lcolsw, As + chunk * 512);
        }
        #pragma unroll
        for (int r = 0; r < 4; ++r) {
            int chunk = r * 8 + w;
            int row = chunk * 8 + lrow;
            gload_lds16(Bg + (size_t)row * DD + kt + lcolsw, Bs + chunk * 512);
        }
        __syncthreads();
        #pragma unroll
        for (int kf = 0; kf < 2; ++kf) {
            bf16x8 a[4], bb[4];
            #pragma unroll
            for (int m = 0; m < 4; ++m) {
                int row = wr * 64 + m * 16 + (l & 15);
                int byte = row * 128 + kf * 64 + (l >> 4) * 16;
                a[m] = *(const bf16x8*)((const char*)As + (byte ^ ((row & 7) << 4)));
            }
            #pragma unroll
            for (int n = 0; n < 4; ++n) {
                int row = wc * 64 + n * 16 + (l & 15);
                int byte = row * 128 + kf * 64 + (l >> 4) * 16;
                bb[n] = *(const bf16x8*)((const char*)Bs + (byte ^ ((row & 7) << 4)));
            }
            #pragma unroll
            for (int m = 0; m < 4; ++m)
                #pragma unroll
                for (int n = 0; n < 4; ++n)
                    acc[m][n] = MFMA16(a[m], bb[n], acc[m][n]);
        }
    }

    // ---- epilogue: add s0c + s1q (keep fp32 S in acc)
    float s1v[4], qmv[4], negq[4];
    #pragma unroll
    for (int n = 0; n < 4; ++n) {
        int j = wc * 64 + n * 16 + (l & 15);
        s1v[n] = s1q[b * LQ + j];
        qmv[n] = qmask[b * LQ + j];
        negq[n] = (1.f - qmv[n]) * NEGINF;
    }
    float s0r[4][4], cmr[4][4];
    #pragma unroll
    for (int m = 0; m < 4; ++m)
        #pragma unroll
        for (int reg = 0; reg < 4; ++reg) {
            int il = wr * 64 + m * 16 + (l >> 4) * 4 + reg;
            s0r[m][reg] = s0c[b * LC + i0 + il];
            cmr[m][reg] = cmask[b * LC + i0 + il];
        }
    #pragma unroll
    for (int m = 0; m < 4; ++m)
        #pragma unroll
        for (int n = 0; n < 4; ++n)
            #pragma unroll
            for (int reg = 0; reg < 4; ++reg)
                acc[m][n][reg] = acc[m][n][reg] + s0r[m][reg] + s1v[n];

    // ---- column-softmax partial stats (over 128 i-rows, c_mask applied)
    #pragma unroll
    for (int n = 0; n < 4; ++n) {
        float x2v[16];
        float mx = NEGINF;
        #pragma unroll
        for (int m = 0; m < 4; ++m)
            #pragma unroll
            for (int reg = 0; reg < 4; ++reg) {
                float cm = cmr[m][reg];
                float x2 = acc[m][n][reg] * cm + (1.f - cm) * NEGINF;
                x2v[m * 4 + reg] = x2;
                mx = fmaxf(mx, x2);
            }
        float ss = 0.f;
        #pragma unroll
        for (int e = 0; e < 16; ++e) ss += __expf(x2v[e] - mx);
        #pragma unroll
        for (int off = 16; off <= 32; off <<= 1) {
            float om = __shfl_xor(mx, off, 64);
            float os = __shfl_xor(ss, off, 64);
            float nm = fmaxf(mx, om);
            ss = ss * __expf(mx - nm) + os * __expf(om - nm);
            mx = nm;
        }
        if (l < 16) {
            size_t idx = ((size_t)b * 32 + blockIdx.x * 2 + wr) * LQ + wc * 64 + n * 16 + l;
            pm[idx] = mx;
            ps[idx] = ss;
        }
    }

    // ---- row-softmax stats: reduce over n (in-thread), l&15 (shfl), wc (LDS)
    #pragma unroll
    for (int m = 0; m < 4; ++m)
        #pragma unroll
        for (int reg = 0; reg < 4; ++reg) {
            float mx = NEGINF;
            #pragma unroll
            for (int n = 0; n < 4; ++n)
                mx = fmaxf(mx, fmaf(acc[m][n][reg], qmv[n], negq[n]));
            #pragma unroll
            for (int o = 1; o <= 8; o <<= 1) mx = fmaxf(mx, __shfl_xor(mx, o, 64));
            float ss = 0.f;
            #pragma unroll
            for (int n = 0; n < 4; ++n)
                ss += __expf(fmaf(acc[m][n][reg], qmv[n], negq[n]) - mx);
            #pragma unroll
            for (int o = 1; o <= 8; o <<= 1) ss += __shfl_xor(ss, o, 64);
            if ((l & 15) == 0) {
                int row = wr * 64 + m * 16 + (l >> 4) * 4 + reg;
                rmLds[row * 4 + wc] = mx;
                rsLds[row * 4 + wc] = ss;
            }
        }
    __syncthreads();
    if (t < 128) {
        float m0 = rmLds[t * 4 + 0], m1 = rmLds[t * 4 + 1];
        float m2 = rmLds[t * 4 + 2], m3 = rmLds[t * 4 + 3];
        float mm = fmaxf(fmaxf(m0, m1), fmaxf(m2, m3));
        float ss = rsLds[t * 4 + 0] * __expf(m0 - mm)
                 + rsLds[t * 4 + 1] * __expf(m1 - mm)
                 + rsLds[t * 4 + 2] * __expf(m2 - mm)
                 + rsLds[t * 4 + 3] * __expf(m3 - mm);
        float rc = mm + logf(ss);
        rowCLds[t] = rc;
        wgtg[(size_t)b * LC + i0 + t] = cmask[b * LC + i0 + t] * __expf(rc);
    }
    __syncthreads();

    // ---- P1b [i][j]: finished row softmax, bf16
    float rCv[4][4];
    #pragma unroll
    for (int m = 0; m < 4; ++m)
        #pragma unroll
        for (int reg = 0; reg < 4; ++reg)
            rCv[m][reg] = rowCLds[wr * 64 + m * 16 + (l >> 4) * 4 + reg];
    #pragma unroll
    for (int m = 0; m < 4; ++m)
        #pragma unroll
        for (int n = 0; n < 4; ++n)
            #pragma unroll
            for (int reg = 0; reg < 4; ++reg) {
                float p = __expf(fmaf(acc[m][n][reg], qmv[n], negq[n]) - rCv[m][reg]);
                int il = wr * 64 + m * 16 + (l >> 4) * 4 + reg;
                int j = wc * 64 + n * 16 + (l & 15);
                P1b[((size_t)b * LC + i0 + il) * LQ + j] = f2b(p);
            }
}

// ---------- k3: split-K partials of A2CT[d,j] = sum_i c[i,d] * (wgt_i * P1[i,j]) ----
// packed short4 transpose staging; 256 blocks (4 ks x 4 tiles x 16 b)
#define K3S 72
__global__ __launch_bounds__(256) void k3_A2C(
        const short* __restrict__ c16, const short* __restrict__ P1b,
        const float* __restrict__ wgtg,
        float* __restrict__ p3) {
    __shared__ short As[128 * K3S];   // [d][i]
    __shared__ short Bs[128 * K3S];   // [j][i]
    int b  = blockIdx.z;
    int ks = blockIdx.y;
    int d0 = (blockIdx.x >> 1) * 128;
    int j0 = (blockIdx.x & 1) * 128;
    int t = threadIdx.x, l = t & 63, w = t >> 6;
    int wr = w >> 1, wc = w & 1;

    f32x4 acc[4][4];
    #pragma unroll
    for (int m = 0; m < 4; ++m)
        #pragma unroll
        for (int n = 0; n < 4; ++n) acc[m][n] = (f32x4){0.f, 0.f, 0.f, 0.f};

    int ii4 = (t >> 4) * 4;                 // i base (4 rows per thread)
    int c8  = (t & 15) * 8;                 // d/j col-block base (8 cols)
    int ip  = ii4 ^ (((c8 >> 3) & 7) << 3); // swizzled i base (const per thread)

    for (int k0 = ks * 512; k0 < ks * 512 + 512; k0 += 64) {
        __syncthreads();
        bf16x8 av[4], pv[4];
        float wv[4];
        #pragma unroll
        for (int r = 0; r < 4; ++r) {
            size_t gi = (size_t)b * LC + k0 + ii4 + r;
            av[r] = *(const bf16x8*)(c16 + gi * DD + d0 + c8);
            pv[r] = *(const bf16x8*)(P1b + gi * LQ + j0 + c8);
            wv[r] = wgtg[gi];
        }
        #pragma unroll
        for (int g = 0; g < 8; ++g) {
            short4 a4, b4;
            a4.x = av[0][g]; a4.y = av[1][g]; a4.z = av[2][g]; a4.w = av[3][g];
            b4.x = f2b(b2f(pv[0][g]) * wv[0]);
            b4.y = f2b(b2f(pv[1][g]) * wv[1]);
            b4.z = f2b(b2f(pv[2][g]) * wv[2]);
            b4.w = f2b(b2f(pv[3][g]) * wv[3]);
            *(short4*)(&As[(c8 + g) * K3S + ip]) = a4;
            *(short4*)(&Bs[(c8 + g) * K3S + ip]) = b4;
        }
        __syncthreads();
        #pragma unroll
        for (int kf = 0; kf < 2; ++kf) {
            bf16x8 a[4], bb[4];
            int colL = kf * 32 + (l >> 4) * 8;
            #pragma unroll
            for (int m = 0; m < 4; ++m) {
                int row = wr * 64 + m * 16 + (l & 15);
                int colP = colL ^ (((row >> 3) & 7) << 3);
                a[m] = *(const bf16x8*)((const char*)As +
                        row * (K3S * 2) + colP * 2);
            }
            #pragma unroll
            for (int n = 0; n < 4; ++n) {
                int row = wc * 64 + n * 16 + (l & 15);
                int colP = colL ^ (((row >> 3) & 7) << 3);
                bb[n] = *(const bf16x8*)((const char*)Bs +
                        row * (K3S * 2) + colP * 2);
            }
            #pragma unroll
            for (int m = 0; m < 4; ++m)
                #pragma unroll
                for (int n = 0; n < 4; ++n)
                    acc[m][n] = MFMA16(a[m], bb[n], acc[m][n]);
        }
    }
    float* P = p3 + (((size_t)b * 4 + ks) * 4 + blockIdx.x) * 16384;
    #pragma unroll
    for (int m = 0; m < 4; ++m)
        #pragma unroll
        for (int n = 0; n < 4; ++n)
            #pragma unroll
            for (int reg = 0; reg < 4; ++reg) {
                int ld = wr * 64 + m * 16 + (l >> 4) * 4 + reg;
                int lj = wc * 64 + n * 16 + (l & 15);
                P[ld * 128 + lj] = acc[m][n][reg];
            }
}

// ---------- k3r: reduce 4 K-splits, apply exp(-colC_j), write bf16 A2CT ----------
__global__ __launch_bounds__(256) void k3r_reduce(
        const float* __restrict__ p3,
        const float* __restrict__ pm, const float* __restrict__ ps,
        short* __restrict__ A2CT) {
    __shared__ float colCs[256];
    int b = blockIdx.y;
    int t = threadIdx.x;
    {
        float m = NEGINF, s = 0.f;
        for (int ch = 0; ch < 32; ++ch) {
            float pmv = pm[((size_t)b * 32 + ch) * LQ + t];
            float psv = ps[((size_t)b * 32 + ch) * LQ + t];
            float mn = fmaxf(m, pmv);
            s = s * __expf(m - mn) + psv * __expf(pmv - mn);
            m = mn;
        }
        colCs[t] = m + logf(s);
    }
    __syncthreads();
    int linear = blockIdx.x * 256 + t;   // 0..16383
    int d = linear >> 6;
    int j4 = (linear & 63) * 4;
    int tile = (d >> 7) * 2 + (j4 >> 7);
    int ld = d & 127, lj = j4 & 127;
    const float* base = p3 + (((size_t)b * 4) * 4 + tile) * 16384 + ld * 128 + lj;
    float4 s = {0.f, 0.f, 0.f, 0.f};
    #pragma unroll
    for (int ks = 0; ks < 4; ++ks) {
        float4 v = *(const float4*)(base + (size_t)ks * 4 * 16384);
        s.x += v.x; s.y += v.y; s.z += v.z; s.w += v.w;
    }
    s.x *= __expf(-colCs[j4 + 0]);
    s.y *= __expf(-colCs[j4 + 1]);
    s.z *= __expf(-colCs[j4 + 2]);
    s.w *= __expf(-colCs[j4 + 3]);
    short4 o;
    o.x = f2b(s.x); o.y = f2b(s.y); o.z = f2b(s.z); o.w = f2b(s.w);
    *(short4*)(A2CT + ((size_t)b * DD + d) * LQ + j4) = o;
}

// ---------- k4: pure GEMM  C2Q = P1@q, Q2C = P1@A2C; writes slabs 1,2,3 ----------
__global__ __launch_bounds__(256) void k4_out(
        const short* __restrict__ P1b, const short* __restrict__ qT16,
        const short* __restrict__ A2CT, const short* __restrict__ c16,
        float* __restrict__ out) {
    __shared__ float Lo1[16][260];
    __shared__ float Lo2[16][260];
    int b = blockIdx.y, i0 = blockIdx.x * 64;
    int t = threadIdx.x, l = t & 63, w = t >> 6;
    int d0w = w * 64;

    f32x4 acc1[4][4], acc2[4][4];
    #pragma unroll
    for (int m = 0; m < 4; ++m)
        #pragma unroll
        for (int n = 0; n < 4; ++n) {
            acc1[m][n] = (f32x4){0.f, 0.f, 0.f, 0.f};
            acc2[m][n] = (f32x4){0.f, 0.f, 0.f, 0.f};
        }
    const short* Sr  = P1b  + ((size_t)b * LC + i0) * LQ;
    const short* qTb = qT16 + (size_t)b * DD * LQ;
    const short* aTb = A2CT + (size_t)b * DD * LQ;

    #pragma unroll 2
    for (int kf = 0; kf < 8; ++kf) {
        int j8 = kf * 32 + (l >> 4) * 8;
        bf16x8 a[4];
        #pragma unroll
        for (int m = 0; m < 4; ++m)
            a[m] = *(const bf16x8*)(Sr + (size_t)(m * 16 + (l & 15)) * LQ + j8);
        #pragma unroll
        for (int n = 0; n < 4; ++n) {
            int d = d0w + n * 16 + (l & 15);
            size_t off = (size_t)d * LQ + j8;
            bf16x8 bq = *(const bf16x8*)(qTb + off);
            bf16x8 ba = *(const bf16x8*)(aTb + off);
            #pragma unroll
            for (int m = 0; m < 4; ++m) {
                acc1[m][n] = MFMA16(a[m], bq, acc1[m][n]);
                acc2[m][n] = MFMA16(a[m], ba, acc2[m][n]);
            }
        }
    }

    const short* cb16 = c16 + (size_t)b * LC * DD;
    #pragma unroll
    for (int m = 0; m < 4; ++m) {
        __syncthreads();
        #pragma unroll
        for (int n = 0; n < 4; ++n) {
            int col = d0w + n * 16 + (l & 15);
            #pragma unroll
            for (int reg = 0; reg < 4; ++reg) {
                int row = (l >> 4) * 4 + reg;
                Lo1[row][col] = acc1[m][n][reg];
                Lo2[row][col] = acc2[m][n][reg];
            }
        }
        __syncthreads();
        #pragma unroll
        for (int rr = 0; rr < 4; ++rr) {
            int row = w * 4 + rr;
            int i = i0 + m * 16 + row;
            float4 f1 = *(const float4*)&Lo1[row][l * 4];
            float4 f2 = *(const float4*)&Lo2[row][l * 4];
            short4 cu = *(const short4*)(cb16 + (size_t)i * DD + l * 4);
            float c0 = b2f(cu.x), c1 = b2f(cu.y), c2 = b2f(cu.z), c3 = b2f(cu.w);
            size_t ob = ((size_t)b * LC + i) * (size_t)(4 * DD);
            float4 p1 = {c0 * f1.x, c1 * f1.y, c2 * f1.z, c3 * f1.w};
            float4 p2 = {c0 * f2.x, c1 * f2.y, c2 * f2.z, c3 * f2.w};
            *(float4*)(out + ob + 256 + l * 4) = f1;
            *(float4*)(out + ob + 512 + l * 4) = p1;
            *(float4*)(out + ob + 768 + l * 4) = p2;
        }
    }
}

extern "C" void kernel_launch(void* const* d_in, const int* in_sizes, int n_in,
                              void* d_out, int out_size, void* d_ws, size_t ws_size,
                              hipStream_t stream) {
    const float* c     = (const float*)d_in[0];
    const float* q     = (const float*)d_in[1];
    const float* cmask = (const float*)d_in[2];
    const float* qmask = (const float*)d_in[3];
    const float* cqw   = (const float*)d_in[4];
    const float* c_w   = (const float*)d_in[5];
    const float* q_w   = (const float*)d_in[6];
    const float* bias  = (const float*)d_in[7];
    float* out = (float*)d_out;

    char* w = (char*)d_ws;
    short* P1b   = (short*)(w);                  // 16,777,216 B  [i][j]
    short* c16   = (short*)(w + 16777216);       // 16,777,216 B  [i][d]
    short* qw16  = (short*)(w + 33554432);       //  2,097,152 B
    short* qT16  = (short*)(w + 35651584);       //  2,097,152 B
    short* A2CT  = (short*)(w + 37748736);       //  2,097,152 B
    float* s0c   = (float*)(w + 39845888);       //    131,072 B
    float* s1q   = (float*)(w + 39976960);       //     16,384 B
    float* pm    = (float*)(w + 39993344);       //    524,288 B
    float* ps    = (float*)(w + 40517632);       //    524,288 B
    float* wgtg  = (float*)(w + 41041920);       //    131,072 B
    float* p3    = (float*)(w + 41172992);       // 16,777,216 B (end 57,950,208)

    prep<<<dim3(NCB + NB * LQ / 64), dim3(256), 0, stream>>>(
        c, q, c_w, cqw, q_w, bias, c16, s0c, qw16, qT16, s1q, out);
    k1_S<<<dim3(LC / 128, NB), dim3(512), 0, stream>>>(
        c16, qw16, cmask, qmask, s0c, s1q, P1b, wgtg, pm, ps);
    k3_A2C<<<dim3(4, 4, NB), dim3(256), 0, stream>>>(
        c16, P1b, wgtg, p3);
    k3r_reduce<<<dim3(64, NB), dim3(256), 0, stream>>>(p3, pm, ps, A2CT);
    k4_out<<<dim3(LC / 64, NB), dim3(256), 0, stream>>>(
        P1b, qT16, A2CT, c16, out);
}

// Round 12
// 114.305 us; speedup vs baseline: 1.1355x; 1.0317x over previous
//
#include <hip/hip_runtime.h>
#include <hip/hip_bf16.h>

#define NB 16
#define LC 2048
#define LQ 256
#define DD 256
#define NEGINF -1e30f

typedef __attribute__((ext_vector_type(8))) short bf16x8;
typedef __attribute__((ext_vector_type(4))) float f32x4;

#define MFMA16(a, b, c) __builtin_amdgcn_mfma_f32_16x16x32_bf16((a), (b), (c), 0, 0, 0)

typedef const unsigned int __attribute__((address_space(1))) glb_u32;
typedef unsigned int __attribute__((address_space(3))) lds_u32;

__device__ __forceinline__ void gload_lds16(const void* g, void* l) {
    __builtin_amdgcn_global_load_lds((glb_u32*)g, (lds_u32*)l, 16, 0, 0);
}

__device__ __forceinline__ short f2b(float x) {
    unsigned u = __float_as_uint(x);
    unsigned r = (u + 0x7fffu + ((u >> 16) & 1u)) >> 16;
    return (short)r;
}
__device__ __forceinline__ float b2f(short s) {
    return __uint_as_float(((unsigned)(unsigned short)s) << 16);
}

// ---------- prep_q: qw16 = bf16(q*cqw), qT16 = bf16(q)^T, s1q ----------
__global__ __launch_bounds__(256) void prep_q(
        const float* __restrict__ q, const float* __restrict__ cqw,
        const float* __restrict__ q_w, const float* __restrict__ bias,
        short* __restrict__ qw16, short* __restrict__ qT16,
        float* __restrict__ s1q) {
    __shared__ float T[64][65];
    int b = blockIdx.y, j0 = blockIdx.x * 64, t = threadIdx.x;
    int dd = t & 63, rg = t >> 6;
    float acc[16];
    #pragma unroll
    for (int i = 0; i < 16; ++i) acc[i] = 0.f;
    for (int dc = 0; dc < 4; ++dc) {
        float wv = cqw[dc * 64 + dd];
        float qwv = q_w[dc * 64 + dd];
        #pragma unroll
        for (int rr = 0; rr < 16; ++rr) {
            int r = rg + 4 * rr;
            float v = q[((size_t)b * LQ + j0 + r) * DD + dc * 64 + dd];
            qw16[((size_t)b * LQ + j0 + r) * DD + dc * 64 + dd] = f2b(v * wv);
            acc[rr] += v * qwv;
            T[dd][r] = v;
        }
        __syncthreads();
        int jj = t & 63;
        for (int dw = t >> 6; dw < 64; dw += 4)
            qT16[((size_t)b * DD + dc * 64 + dw) * LQ + j0 + jj] = f2b(T[dw][jj]);
        __syncthreads();
    }
    float bv = bias[0];
    #pragma unroll
    for (int rr = 0; rr < 16; ++rr) {
        float s = acc[rr];
        #pragma unroll
        for (int o = 32; o > 0; o >>= 1) s += __shfl_xor(s, o, 64);
        if (dd == 0) s1q[b * LQ + j0 + rg + 4 * rr] = s + bv;
    }
}

// ---------- k1: S tile [128 x 256] = c @ (q*cqw)^T + s0 + s1 (8 waves)
// A staged in-reg from fp32 c; side-effects: c16, out slab0, s0c (in LDS).
// outputs: P1b = bf16(finished row softmax), wgtg = cm*exp(rowC), pm/ps
__global__ __launch_bounds__(512) void k1_S(
        const float* __restrict__ c, const short* __restrict__ qw16,
        const float* __restrict__ c_w,
        const float* __restrict__ cmask, const float* __restrict__ qmask,
        const float* __restrict__ s1q,
        short* __restrict__ c16, short* __restrict__ P1b,
        float* __restrict__ wgtg,
        float* __restrict__ pm, float* __restrict__ ps,
        float* __restrict__ out) {
    __shared__ short As[128 * 64];
    __shared__ short Bs[256 * 64];
    __shared__ float rmLds[128 * 4];
    __shared__ float rsLds[128 * 4];
    __shared__ float rowCLds[128];
    __shared__ float s0Lds[128];
    int b  = blockIdx.y;
    int i0 = blockIdx.x * 128;
    int t = threadIdx.x;
    int l = t & 63, w = t >> 6;
    int wr = w >> 2, wc = w & 3;

    f32x4 acc[4][4];
    #pragma unroll
    for (int m = 0; m < 4; ++m)
        #pragma unroll
        for (int n = 0; n < 4; ++n) acc[m][n] = (f32x4){0.f, 0.f, 0.f, 0.f};

    const float* cg = c + ((size_t)b * LC + i0) * DD;
    const short* Bg = qw16 + ((size_t)b * LQ) * DD;
    short* c16g = c16 + ((size_t)b * LC + i0) * DD;
    int lrow = l >> 3;
    int lcolsw = ((l & 7) ^ lrow) * 8;   // B staging source swizzle
    int csA = (l & 7) ^ lrow;            // A source col-block (swizzle via source)
    float s0acc[2] = {0.f, 0.f};

    for (int kt = 0; kt < DD; kt += 64) {
        __syncthreads();
        #pragma unroll
        for (int r = 0; r < 4; ++r) {        // B: async global->LDS
            int chunk = r * 8 + w;
            int row = chunk * 8 + lrow;
            gload_lds16(Bg + (size_t)row * DD + kt + lcolsw, Bs + chunk * 512);
        }
        #pragma unroll
        for (int r = 0; r < 2; ++r) {        // A: fp32 reg-stage + cvt + side writes
            int chunk = r * 8 + w;
            int row = chunk * 8 + lrow;      // 0..127
            const float* src = cg + (size_t)row * DD + kt + csA * 8;
            float4 v0 = *(const float4*)(src);
            float4 v1 = *(const float4*)(src + 4);
            float4 w0 = *(const float4*)(c_w + kt + csA * 8);
            float4 w1 = *(const float4*)(c_w + kt + csA * 8 + 4);
            s0acc[r] += v0.x * w0.x + v0.y * w0.y + v0.z * w0.z + v0.w * w0.w
                      + v1.x * w1.x + v1.y * w1.y + v1.z * w1.z + v1.w * w1.w;
            bf16x8 pk;
            pk[0] = f2b(v0.x); pk[1] = f2b(v0.y); pk[2] = f2b(v0.z); pk[3] = f2b(v0.w);
            pk[4] = f2b(v1.x); pk[5] = f2b(v1.y); pk[6] = f2b(v1.z); pk[7] = f2b(v1.w);
            *(bf16x8*)(As + chunk * 512 + l * 8) = pk;   // same layout as gload dest
            *(bf16x8*)(c16g + (size_t)row * DD + kt + csA * 8) = pk;
            size_t ob = ((size_t)b * LC + i0 + row) * (size_t)(4 * DD) + kt + csA * 8;
            *(float4*)(out + ob)     = v0;
            *(float4*)(out + ob + 4) = v1;
        }
        __syncthreads();
        #pragma unroll
        for (int kf = 0; kf < 2; ++kf) {
            bf16x8 a[4], bb[4];
            #pragma unroll
            for (int m = 0; m < 4; ++m) {
                int row = wr * 64 + m * 16 + (l & 15);
                int byte = row * 128 + kf * 64 + (l >> 4) * 16;
                a[m] = *(const bf16x8*)((const char*)As + (byte ^ ((row & 7) << 4)));
            }
            #pragma unroll
            for (int n = 0; n < 4; ++n) {
                int row = wc * 64 + n * 16 + (l & 15);
                int byte = row * 128 + kf * 64 + (l >> 4) * 16;
                bb[n] = *(const bf16x8*)((const char*)Bs + (byte ^ ((row & 7) << 4)));
            }
            #pragma unroll
            for (int m = 0; m < 4; ++m)
                #pragma unroll
                for (int n = 0; n < 4; ++n)
                    acc[m][n] = MFMA16(a[m], bb[n], acc[m][n]);
        }
    }

    // ---- s0c: reduce 8-lane partials per row into LDS
    #pragma unroll
    for (int r = 0; r < 2; ++r) {
        float s = s0acc[r];
        s += __shfl_xor(s, 1, 64);
        s += __shfl_xor(s, 2, 64);
        s += __shfl_xor(s, 4, 64);
        if ((l & 7) == 0) s0Lds[(r * 8 + w) * 8 + lrow] = s;
    }
    __syncthreads();

    // ---- epilogue: add s0c + s1q (keep fp32 S in acc)
    float s1v[4], qmv[4], negq[4];
    #pragma unroll
    for (int n = 0; n < 4; ++n) {
        int j = wc * 64 + n * 16 + (l & 15);
        s1v[n] = s1q[b * LQ + j];
        qmv[n] = qmask[b * LQ + j];
        negq[n] = (1.f - qmv[n]) * NEGINF;
    }
    float s0r[4][4], cmr[4][4];
    #pragma unroll
    for (int m = 0; m < 4; ++m)
        #pragma unroll
        for (int reg = 0; reg < 4; ++reg) {
            int il = wr * 64 + m * 16 + (l >> 4) * 4 + reg;
            s0r[m][reg] = s0Lds[il];
            cmr[m][reg] = cmask[b * LC + i0 + il];
        }
    #pragma unroll
    for (int m = 0; m < 4; ++m)
        #pragma unroll
        for (int n = 0; n < 4; ++n)
            #pragma unroll
            for (int reg = 0; reg < 4; ++reg)
                acc[m][n][reg] = acc[m][n][reg] + s0r[m][reg] + s1v[n];

    // ---- column-softmax partial stats (over 128 i-rows, c_mask applied)
    #pragma unroll
    for (int n = 0; n < 4; ++n) {
        float x2v[16];
        float mx = NEGINF;
        #pragma unroll
        for (int m = 0; m < 4; ++m)
            #pragma unroll
            for (int reg = 0; reg < 4; ++reg) {
                float cm = cmr[m][reg];
                float x2 = acc[m][n][reg] * cm + (1.f - cm) * NEGINF;
                x2v[m * 4 + reg] = x2;
                mx = fmaxf(mx, x2);
            }
        float ss = 0.f;
        #pragma unroll
        for (int e = 0; e < 16; ++e) ss += __expf(x2v[e] - mx);
        #pragma unroll
        for (int off = 16; off <= 32; off <<= 1) {
            float om = __shfl_xor(mx, off, 64);
            float os = __shfl_xor(ss, off, 64);
            float nm = fmaxf(mx, om);
            ss = ss * __expf(mx - nm) + os * __expf(om - nm);
            mx = nm;
        }
        if (l < 16) {
            size_t idx = ((size_t)b * 32 + blockIdx.x * 2 + wr) * LQ + wc * 64 + n * 16 + l;
            pm[idx] = mx;
            ps[idx] = ss;
        }
    }

    // ---- row-softmax stats: reduce over n (in-thread), l&15 (shfl), wc (LDS)
    #pragma unroll
    for (int m = 0; m < 4; ++m)
        #pragma unroll
        for (int reg = 0; reg < 4; ++reg) {
            float mx = NEGINF;
            #pragma unroll
            for (int n = 0; n < 4; ++n)
                mx = fmaxf(mx, fmaf(acc[m][n][reg], qmv[n], negq[n]));
            #pragma unroll
            for (int o = 1; o <= 8; o <<= 1) mx = fmaxf(mx, __shfl_xor(mx, o, 64));
            float ss = 0.f;
            #pragma unroll
            for (int n = 0; n < 4; ++n)
                ss += __expf(fmaf(acc[m][n][reg], qmv[n], negq[n]) - mx);
            #pragma unroll
            for (int o = 1; o <= 8; o <<= 1) ss += __shfl_xor(ss, o, 64);
            if ((l & 15) == 0) {
                int row = wr * 64 + m * 16 + (l >> 4) * 4 + reg;
                rmLds[row * 4 + wc] = mx;
                rsLds[row * 4 + wc] = ss;
            }
        }
    __syncthreads();
    if (t < 128) {
        float m0 = rmLds[t * 4 + 0], m1 = rmLds[t * 4 + 1];
        float m2 = rmLds[t * 4 + 2], m3 = rmLds[t * 4 + 3];
        float mm = fmaxf(fmaxf(m0, m1), fmaxf(m2, m3));
        float ss = rsLds[t * 4 + 0] * __expf(m0 - mm)
                 + rsLds[t * 4 + 1] * __expf(m1 - mm)
                 + rsLds[t * 4 + 2] * __expf(m2 - mm)
                 + rsLds[t * 4 + 3] * __expf(m3 - mm);
        float rc = mm + logf(ss);
        rowCLds[t] = rc;
        wgtg[(size_t)b * LC + i0 + t] = cmask[b * LC + i0 + t] * __expf(rc);
    }
    __syncthreads();

    // ---- P1b [i][j]: finished row softmax, bf16
    float rCv[4][4];
    #pragma unroll
    for (int m = 0; m < 4; ++m)
        #pragma unroll
        for (int reg = 0; reg < 4; ++reg)
            rCv[m][reg] = rowCLds[wr * 64 + m * 16 + (l >> 4) * 4 + reg];
    #pragma unroll
    for (int m = 0; m < 4; ++m)
        #pragma unroll
        for (int n = 0; n < 4; ++n)
            #pragma unroll
            for (int reg = 0; reg < 4; ++reg) {
                float p = __expf(fmaf(acc[m][n][reg], qmv[n], negq[n]) - rCv[m][reg]);
                int il = wr * 64 + m * 16 + (l >> 4) * 4 + reg;
                int j = wc * 64 + n * 16 + (l & 15);
                P1b[((size_t)b * LC + i0 + il) * LQ + j] = f2b(p);
            }
}

// ---------- k3: split-K partials of A2CT[d,j] = sum_i c[i,d] * (wgt_i * P1[i,j]) ----
#define K3S 72
__global__ __launch_bounds__(256) void k3_A2C(
        const short* __restrict__ c16, const short* __restrict__ P1b,
        const float* __restrict__ wgtg,
        float* __restrict__ p3) {
    __shared__ short As[128 * K3S];   // [d][i]
    __shared__ short Bs[128 * K3S];   // [j][i]
    int b  = blockIdx.z;
    int ks = blockIdx.y;
    int d0 = (blockIdx.x >> 1) * 128;
    int j0 = (blockIdx.x & 1) * 128;
    int t = threadIdx.x, l = t & 63, w = t >> 6;
    int wr = w >> 1, wc = w & 1;

    f32x4 acc[4][4];
    #pragma unroll
    for (int m = 0; m < 4; ++m)
        #pragma unroll
        for (int n = 0; n < 4; ++n) acc[m][n] = (f32x4){0.f, 0.f, 0.f, 0.f};

    int ii4 = (t >> 4) * 4;
    int c8  = (t & 15) * 8;
    int ip  = ii4 ^ (((c8 >> 3) & 7) << 3);

    for (int k0 = ks * 512; k0 < ks * 512 + 512; k0 += 64) {
        __syncthreads();
        bf16x8 av[4], pv[4];
        float wv[4];
        #pragma unroll
        for (int r = 0; r < 4; ++r) {
            size_t gi = (size_t)b * LC + k0 + ii4 + r;
            av[r] = *(const bf16x8*)(c16 + gi * DD + d0 + c8);
            pv[r] = *(const bf16x8*)(P1b + gi * LQ + j0 + c8);
            wv[r] = wgtg[gi];
        }
        #pragma unroll
        for (int g = 0; g < 8; ++g) {
            short4 a4, b4;
            a4.x = av[0][g]; a4.y = av[1][g]; a4.z = av[2][g]; a4.w = av[3][g];
            b4.x = f2b(b2f(pv[0][g]) * wv[0]);
            b4.y = f2b(b2f(pv[1][g]) * wv[1]);
            b4.z = f2b(b2f(pv[2][g]) * wv[2]);
            b4.w = f2b(b2f(pv[3][g]) * wv[3]);
            *(short4*)(&As[(c8 + g) * K3S + ip]) = a4;
            *(short4*)(&Bs[(c8 + g) * K3S + ip]) = b4;
        }
        __syncthreads();
        #pragma unroll
        for (int kf = 0; kf < 2; ++kf) {
            bf16x8 a[4], bb[4];
            int colL = kf * 32 + (l >> 4) * 8;
            #pragma unroll
            for (int m = 0; m < 4; ++m) {
                int row = wr * 64 + m * 16 + (l & 15);
                int colP = colL ^ (((row >> 3) & 7) << 3);
                a[m] = *(const bf16x8*)((const char*)As + row * (K3S * 2) + colP * 2);
            }
            #pragma unroll
            for (int n = 0; n < 4; ++n) {
                int row = wc * 64 + n * 16 + (l & 15);
                int colP = colL ^ (((row >> 3) & 7) << 3);
                bb[n] = *(const bf16x8*)((const char*)Bs + row * (K3S * 2) + colP * 2);
            }
            #pragma unroll
            for (int m = 0; m < 4; ++m)
                #pragma unroll
                for (int n = 0; n < 4; ++n)
                    acc[m][n] = MFMA16(a[m], bb[n], acc[m][n]);
        }
    }
    float* P = p3 + (((size_t)b * 4 + ks) * 4 + blockIdx.x) * 16384;
    #pragma unroll
    for (int m = 0; m < 4; ++m)
        #pragma unroll
        for (int n = 0; n < 4; ++n)
            #pragma unroll
            for (int reg = 0; reg < 4; ++reg) {
                int ld = wr * 64 + m * 16 + (l >> 4) * 4 + reg;
                int lj = wc * 64 + n * 16 + (l & 15);
                P[ld * 128 + lj] = acc[m][n][reg];
            }
}

// ---------- k3r: reduce 4 K-splits, apply exp(-colC_j), write bf16 A2CT ----------
__global__ __launch_bounds__(256) void k3r_reduce(
        const float* __restrict__ p3,
        const float* __restrict__ pm, const float* __restrict__ ps,
        short* __restrict__ A2CT) {
    __shared__ float colCs[256];
    int b = blockIdx.y;
    int t = threadIdx.x;
    {
        float m = NEGINF, s = 0.f;
        for (int ch = 0; ch < 32; ++ch) {
            float pmv = pm[((size_t)b * 32 + ch) * LQ + t];
            float psv = ps[((size_t)b * 32 + ch) * LQ + t];
            float mn = fmaxf(m, pmv);
            s = s * __expf(m - mn) + psv * __expf(pmv - mn);
            m = mn;
        }
        colCs[t] = m + logf(s);
    }
    __syncthreads();
    int linear = blockIdx.x * 256 + t;   // 0..16383
    int d = linear >> 6;
    int j4 = (linear & 63) * 4;
    int tile = (d >> 7) * 2 + (j4 >> 7);
    int ld = d & 127, lj = j4 & 127;
    const float* base = p3 + (((size_t)b * 4) * 4 + tile) * 16384 + ld * 128 + lj;
    float4 s = {0.f, 0.f, 0.f, 0.f};
    #pragma unroll
    for (int ks = 0; ks < 4; ++ks) {
        float4 v = *(const float4*)(base + (size_t)ks * 4 * 16384);
        s.x += v.x; s.y += v.y; s.z += v.z; s.w += v.w;
    }
    s.x *= __expf(-colCs[j4 + 0]);
    s.y *= __expf(-colCs[j4 + 1]);
    s.z *= __expf(-colCs[j4 + 2]);
    s.w *= __expf(-colCs[j4 + 3]);
    short4 o;
    o.x = f2b(s.x); o.y = f2b(s.y); o.z = f2b(s.z); o.w = f2b(s.w);
    *(short4*)(A2CT + ((size_t)b * DD + d) * LQ + j4) = o;
}

// ---------- k4: pure GEMM  C2Q = P1@q, Q2C = P1@A2C; writes slabs 1,2,3 ----------
__global__ __launch_bounds__(256) void k4_out(
        const short* __restrict__ P1b, const short* __restrict__ qT16,
        const short* __restrict__ A2CT, const short* __restrict__ c16,
        float* __restrict__ out) {
    __shared__ float Lo1[16][260];
    __shared__ float Lo2[16][260];
    int b = blockIdx.y, i0 = blockIdx.x * 64;
    int t = threadIdx.x, l = t & 63, w = t >> 6;
    int d0w = w * 64;

    f32x4 acc1[4][4], acc2[4][4];
    #pragma unroll
    for (int m = 0; m < 4; ++m)
        #pragma unroll
        for (int n = 0; n < 4; ++n) {
            acc1[m][n] = (f32x4){0.f, 0.f, 0.f, 0.f};
            acc2[m][n] = (f32x4){0.f, 0.f, 0.f, 0.f};
        }
    const short* Sr  = P1b  + ((size_t)b * LC + i0) * LQ;
    const short* qTb = qT16 + (size_t)b * DD * LQ;
    const short* aTb = A2CT + (size_t)b * DD * LQ;

    #pragma unroll 2
    for (int kf = 0; kf < 8; ++kf) {
        int j8 = kf * 32 + (l >> 4) * 8;
        bf16x8 a[4];
        #pragma unroll
        for (int m = 0; m < 4; ++m)
            a[m] = *(const bf16x8*)(Sr + (size_t)(m * 16 + (l & 15)) * LQ + j8);
        #pragma unroll
        for (int n = 0; n < 4; ++n) {
            int d = d0w + n * 16 + (l & 15);
            size_t off = (size_t)d * LQ + j8;
            bf16x8 bq = *(const bf16x8*)(qTb + off);
            bf16x8 ba = *(const bf16x8*)(aTb + off);
            #pragma unroll
            for (int m = 0; m < 4; ++m) {
                acc1[m][n] = MFMA16(a[m], bq, acc1[m][n]);
                acc2[m][n] = MFMA16(a[m], ba, acc2[m][n]);
            }
        }
    }

    const short* cb16 = c16 + (size_t)b * LC * DD;
    #pragma unroll
    for (int m = 0; m < 4; ++m) {
        __syncthreads();
        #pragma unroll
        for (int n = 0; n < 4; ++n) {
            int col = d0w + n * 16 + (l & 15);
            #pragma unroll
            for (int reg = 0; reg < 4; ++reg) {
                int row = (l >> 4) * 4 + reg;
                Lo1[row][col] = acc1[m][n][reg];
                Lo2[row][col] = acc2[m][n][reg];
            }
        }
        __syncthreads();
        #pragma unroll
        for (int rr = 0; rr < 4; ++rr) {
            int row = w * 4 + rr;
            int i = i0 + m * 16 + row;
            float4 f1 = *(const float4*)&Lo1[row][l * 4];
            float4 f2 = *(const float4*)&Lo2[row][l * 4];
            short4 cu = *(const short4*)(cb16 + (size_t)i * DD + l * 4);
            float c0 = b2f(cu.x), c1 = b2f(cu.y), c2 = b2f(cu.z), c3 = b2f(cu.w);
            size_t ob = ((size_t)b * LC + i) * (size_t)(4 * DD);
            float4 p1 = {c0 * f1.x, c1 * f1.y, c2 * f1.z, c3 * f1.w};
            float4 p2 = {c0 * f2.x, c1 * f2.y, c2 * f2.z, c3 * f2.w};
            *(float4*)(out + ob + 256 + l * 4) = f1;
            *(float4*)(out + ob + 512 + l * 4) = p1;
            *(float4*)(out + ob + 768 + l * 4) = p2;
        }
    }
}

extern "C" void kernel_launch(void* const* d_in, const int* in_sizes, int n_in,
                              void* d_out, int out_size, void* d_ws, size_t ws_size,
                              hipStream_t stream) {
    const float* c     = (const float*)d_in[0];
    const float* q     = (const float*)d_in[1];
    const float* cmask = (const float*)d_in[2];
    const float* qmask = (const float*)d_in[3];
    const float* cqw   = (const float*)d_in[4];
    const float* c_w   = (const float*)d_in[5];
    const float* q_w   = (const float*)d_in[6];
    const float* bias  = (const float*)d_in[7];
    float* out = (float*)d_out;

    char* w = (char*)d_ws;
    short* P1b   = (short*)(w);                  // 16,777,216 B  [i][j]
    short* c16   = (short*)(w + 16777216);       // 16,777,216 B  [i][d]
    short* qw16  = (short*)(w + 33554432);       //  2,097,152 B
    short* qT16  = (short*)(w + 35651584);       //  2,097,152 B
    short* A2CT  = (short*)(w + 37748736);       //  2,097,152 B
    float* s1q   = (float*)(w + 39976960);       //     16,384 B
    float* pm    = (float*)(w + 39993344);       //    524,288 B
    float* ps    = (float*)(w + 40517632);       //    524,288 B
    float* wgtg  = (float*)(w + 41041920);       //    131,072 B
    float* p3    = (float*)(w + 41172992);       // 16,777,216 B (end 57,950,208)

    prep_q<<<dim3(LQ / 64, NB), dim3(256), 0, stream>>>(
        q, cqw, q_w, bias, qw16, qT16, s1q);
    k1_S<<<dim3(LC / 128, NB), dim3(512), 0, stream>>>(
        c, qw16, c_w, cmask, qmask, s1q, c16, P1b, wgtg, pm, ps, out);
    k3_A2C<<<dim3(4, 4, NB), dim3(256), 0, stream>>>(
        c16, P1b, wgtg, p3);
    k3r_reduce<<<dim3(64, NB), dim3(256), 0, stream>>>(p3, pm, ps, A2CT);
    k4_out<<<dim3(LC / 64, NB), dim3(256), 0, stream>>>(
        P1b, qT16, A2CT, c16, out);
}